// Round 2
// baseline (2958.968 us; speedup 1.0000x reference)
//
#include <hip/hip_runtime.h>

// LSTM: SEQ=512, B=64, IN=256, H=512. Inputs/outputs are FP32 (reference dtype;
// round-1 NaN proved bf16 reinterpretation was wrong). Compute: bf16 MFMA
// (operands RNE-rounded), fp32 accumulate/pointwise/state.
//
// Decomposition: 4 batch-groups of 16 (recurrence independent across batch) x
// 16 H-slice blocks (32 hidden x 4 gates each). Persistent kernel, 512 steps.
// h exchanged through d_out (h_seq) with one release-counter per (group,step)
// in d_ws. grp = blockIdx&3 keeps a group's 16 blocks on ~2 XCDs under
// round-robin dispatch (perf heuristic only).

#define T_STEPS 512
#define BATCH   64
#define IN_D    256
#define HID     512
#define NGROUP  4
#define NSLICE  16
#define BLK_B   16
#define BLK_H   32
#define THREADS 512

#define HPAD 536   // bf16 elems; 536*2B=1072B row stride, 16B aligned
#define XPAD 280

using short8  = __attribute__((ext_vector_type(8))) short;
using float4v = __attribute__((ext_vector_type(4))) float;

__device__ __forceinline__ unsigned short f2bf(float f) {
    union { float f; unsigned int i; } v; v.f = f;
    unsigned int r = v.i + 0x7fff + ((v.i >> 16) & 1);
    return (unsigned short)(r >> 16);
}
__device__ __forceinline__ float sigm(float v) { return 1.0f / (1.0f + __expf(-v)); }
__device__ __forceinline__ float tanh_(float v) { return 2.0f / (1.0f + __expf(-2.0f * v)) - 1.0f; }

__global__ __launch_bounds__(256, 1) void lstm_init_flags(unsigned int* flags, int n) {
    int i = blockIdx.x * blockDim.x + threadIdx.x;
    if (i < n) flags[i] = 0u;
}

__global__ __launch_bounds__(THREADS, 2) void lstm_persist(
    const float* __restrict__ x,
    const float* __restrict__ h0,
    const float* __restrict__ c0,
    const float* __restrict__ Wf, const float* __restrict__ Wfb,
    const float* __restrict__ Uf, const float* __restrict__ Ufb,
    const float* __restrict__ Wi, const float* __restrict__ Wib,
    const float* __restrict__ Ui, const float* __restrict__ Uib,
    const float* __restrict__ Wo, const float* __restrict__ Wob,
    const float* __restrict__ Uo, const float* __restrict__ Uob,
    const float* __restrict__ Wc, const float* __restrict__ Wcb,
    const float* __restrict__ Uc, const float* __restrict__ Ucb,
    float* out,                 // h_seq (T,B,H) | h (B,H) | c (B,H), fp32
    unsigned int* flags)        // [NGROUP][T] producer counters
{
    __shared__ unsigned short h_lds[BLK_B * HPAD];   // bf16 h tile
    __shared__ unsigned short x_lds[BLK_B * XPAD];   // bf16 x tile
    __shared__ float g_lds[8 * 256];                 // 8 waves x (16b x 16h) fp32
    __shared__ float c_lds[BLK_B * BLK_H];           // fp32 cell state

    const int tid  = threadIdx.x;
    const int lane = tid & 63;
    const int wave = tid >> 6;            // 0..7
    const int gate = wave >> 1;           // 0:f 1:i 2:o 3:c
    const int hlf  = wave & 1;            // 16-hid half of the 32
    const int grp  = blockIdx.x & 3;      // batch group 0..3 (XCD-clustered)
    const int slc  = blockIdx.x >> 2;     // hid slice 0..15
    const int bb   = grp * BLK_B;
    const int hbase= slc * BLK_H;
    const int lm   = lane & 15;
    const int lq   = lane >> 4;

    const float* Ug  = (gate == 0) ? Uf : (gate == 1) ? Ui : (gate == 2) ? Uo : Uc;
    const float* Wg  = (gate == 0) ? Wf : (gate == 1) ? Wi : (gate == 2) ? Wo : Wc;
    const float* Wbg = (gate == 0) ? Wfb : (gate == 1) ? Wib : (gate == 2) ? Wob : Wcb;
    const float* Ubg = (gate == 0) ? Ufb : (gate == 1) ? Uib : (gate == 2) ? Uob : Ucb;
    const int ng = hbase + hlf * 16 + lm;   // this lane's gate-output row (B-op n)

    // ---- register-resident bf16 weight fragments: b[j] = W[ng][k0+j] ----
    short8 ufrag[16];
#pragma unroll
    for (int ks = 0; ks < 16; ++ks) {
        const float* p = Ug + (size_t)ng * HID + ks * 32 + lq * 8;
        float4 u0 = *(const float4*)(p), u1 = *(const float4*)(p + 4);
        short8 s;
        s[0]=f2bf(u0.x); s[1]=f2bf(u0.y); s[2]=f2bf(u0.z); s[3]=f2bf(u0.w);
        s[4]=f2bf(u1.x); s[5]=f2bf(u1.y); s[6]=f2bf(u1.z); s[7]=f2bf(u1.w);
        ufrag[ks] = s;
    }
    short8 wfrag[8];
#pragma unroll
    for (int ks = 0; ks < 8; ++ks) {
        const float* p = Wg + (size_t)ng * IN_D + ks * 32 + lq * 8;
        float4 u0 = *(const float4*)(p), u1 = *(const float4*)(p + 4);
        short8 s;
        s[0]=f2bf(u0.x); s[1]=f2bf(u0.y); s[2]=f2bf(u0.z); s[3]=f2bf(u0.w);
        s[4]=f2bf(u1.x); s[5]=f2bf(u1.y); s[6]=f2bf(u1.z); s[7]=f2bf(u1.w);
        wfrag[ks] = s;
    }
    const float bias = Wbg[ng] + Ubg[ng];

    const int row = tid >> 5, seg = tid & 31;   // staging coords (16 x 32)

    // ---- initial staging: x0 (bf16), h0 (bf16), c0 (fp32) ----
    {
        const float* px = x + ((size_t)0 * BATCH + bb + row) * IN_D + seg * 8;
        float4 a0 = *(const float4*)(px), a1 = *(const float4*)(px + 4);
        unsigned short* d = x_lds + row * XPAD + seg * 8;
        d[0]=f2bf(a0.x); d[1]=f2bf(a0.y); d[2]=f2bf(a0.z); d[3]=f2bf(a0.w);
        d[4]=f2bf(a1.x); d[5]=f2bf(a1.y); d[6]=f2bf(a1.z); d[7]=f2bf(a1.w);

        const float* ph = h0 + (size_t)(bb + row) * HID + seg * 16;
        unsigned short* dh = h_lds + row * HPAD + seg * 16;
#pragma unroll
        for (int q = 0; q < 4; ++q) {
            float4 hq = *(const float4*)(ph + q * 4);
            dh[q*4+0]=f2bf(hq.x); dh[q*4+1]=f2bf(hq.y);
            dh[q*4+2]=f2bf(hq.z); dh[q*4+3]=f2bf(hq.w);
        }
        c_lds[row * BLK_H + seg] = c0[(size_t)(bb + row) * HID + hbase + seg];
    }
    // prefetch x_1
    float4 xn0, xn1;
    {
        const float* px = x + ((size_t)1 * BATCH + bb + row) * IN_D + seg * 8;
        xn0 = *(const float4*)(px); xn1 = *(const float4*)(px + 4);
    }
    __syncthreads();

    unsigned int* const cnt = flags + (size_t)grp * T_STEPS;
    float* const out_h = out + (size_t)T_STEPS * BATCH * HID;
    float* const out_c = out_h + (size_t)BATCH * HID;

    for (int t = 0; t < T_STEPS; ++t) {
        // ---- gates = bias + x_t@W^T + h@U^T : 16x16x32 bf16 MFMA ----
        float4v acc0 = {bias, bias, bias, bias};
        float4v acc1 = {0.f, 0.f, 0.f, 0.f};
#pragma unroll
        for (int ks = 0; ks < 8; ++ks) {
            short8 a = *(const short8*)(x_lds + lm * XPAD + ks * 32 + lq * 8);
            if (ks & 1) acc1 = __builtin_amdgcn_mfma_f32_16x16x32_bf16(a, wfrag[ks], acc1, 0, 0, 0);
            else        acc0 = __builtin_amdgcn_mfma_f32_16x16x32_bf16(a, wfrag[ks], acc0, 0, 0, 0);
        }
#pragma unroll
        for (int ks = 0; ks < 16; ++ks) {
            short8 a = *(const short8*)(h_lds + lm * HPAD + ks * 32 + lq * 8);
            if (ks & 1) acc1 = __builtin_amdgcn_mfma_f32_16x16x32_bf16(a, ufrag[ks], acc1, 0, 0, 0);
            else        acc0 = __builtin_amdgcn_mfma_f32_16x16x32_bf16(a, ufrag[ks], acc0, 0, 0, 0);
        }
        float4v acc = acc0 + acc1;
        // D layout: col(N=hid)=lane&15, row(M=batch)=lq*4+r
#pragma unroll
        for (int r = 0; r < 4; ++r)
            g_lds[wave * 256 + (lq * 4 + r) * 16 + lm] = acc[r];
        __syncthreads();   // MFMA reads of x_lds/h_lds done; gates visible

        // rotate x (registers -> LDS for step t+1; prefetch t+2)
        if (t + 1 < T_STEPS) {
            unsigned short* d = x_lds + row * XPAD + seg * 8;
            d[0]=f2bf(xn0.x); d[1]=f2bf(xn0.y); d[2]=f2bf(xn0.z); d[3]=f2bf(xn0.w);
            d[4]=f2bf(xn1.x); d[5]=f2bf(xn1.y); d[6]=f2bf(xn1.z); d[7]=f2bf(xn1.w);
            int tn = (t + 2 < T_STEPS) ? (t + 2) : (T_STEPS - 1);
            const float* px = x + ((size_t)tn * BATCH + bb + row) * IN_D + seg * 8;
            xn0 = *(const float4*)(px); xn1 = *(const float4*)(px + 4);
        }

        // ---- pointwise: one (batch,hid) element per thread; fp32 ----
        {
            int b = row, n = seg;                 // 16 x 32
            int hf2 = n >> 4, nn = n & 15;
            float fpre = g_lds[(0 * 2 + hf2) * 256 + b * 16 + nn];
            float ipre = g_lds[(1 * 2 + hf2) * 256 + b * 16 + nn];
            float opre = g_lds[(2 * 2 + hf2) * 256 + b * 16 + nn];
            float gpre = g_lds[(3 * 2 + hf2) * 256 + b * 16 + nn];
            float fv = sigm(fpre), iv = sigm(ipre), ov = sigm(opre);
            float gv = tanh_(gpre);
            float cv = fv * c_lds[b * BLK_H + n] + iv * gv;
            c_lds[b * BLK_H + n] = cv;
            float hv = ov * tanh_(cv);
            out[((size_t)t * BATCH + bb + b) * HID + hbase + n] = hv;
            if (t == T_STEPS - 1) {
                out_h[(size_t)(bb + b) * HID + hbase + n] = hv;
                out_c[(size_t)(bb + b) * HID + hbase + n] = cv;
            }
        }
        __syncthreads();   // drains vmcnt: our h stores are in L2 before release

        // ---- release: publish this slice's h for step t ----
        if (tid == 0) {
            __threadfence();   // agent release: L2 writeback to coherent point
            __hip_atomic_fetch_add(&cnt[t], 1u, __ATOMIC_RELEASE, __HIP_MEMORY_SCOPE_AGENT);
        }

        if (t + 1 < T_STEPS) {
            // ---- acquire: wait for all 16 producers of this group ----
            if (tid == 0) {
                while (__hip_atomic_load(&cnt[t], __ATOMIC_ACQUIRE, __HIP_MEMORY_SCOPE_AGENT)
                       < (unsigned)NSLICE) {
                    __builtin_amdgcn_s_sleep(1);
                }
                __threadfence();   // acquire side: invalidate caches for h reads
            }
            __syncthreads();
            // stage h_t (fp32 in out -> bf16 LDS), full 512 wide, our 16 batches
            {
                const float* src = out + ((size_t)t * BATCH + bb + row) * HID + seg * 16;
                unsigned short* dh = h_lds + row * HPAD + seg * 16;
#pragma unroll
                for (int q = 0; q < 4; ++q) {
                    float4 hq = *(const float4*)(src + q * 4);
                    dh[q*4+0]=f2bf(hq.x); dh[q*4+1]=f2bf(hq.y);
                    dh[q*4+2]=f2bf(hq.z); dh[q*4+3]=f2bf(hq.w);
                }
            }
            __syncthreads();
        }
    }
}

extern "C" void kernel_launch(void* const* d_in, const int* in_sizes, int n_in,
                              void* d_out, int out_size, void* d_ws, size_t ws_size,
                              hipStream_t stream) {
    (void)in_sizes; (void)n_in; (void)out_size; (void)ws_size;
    const float* x   = (const float*)d_in[0];
    const float* h0  = (const float*)d_in[1];
    const float* c0  = (const float*)d_in[2];
    const float* Wf  = (const float*)d_in[3];
    const float* Wfb = (const float*)d_in[4];
    const float* Uf  = (const float*)d_in[5];
    const float* Ufb = (const float*)d_in[6];
    const float* Wi  = (const float*)d_in[7];
    const float* Wib = (const float*)d_in[8];
    const float* Ui  = (const float*)d_in[9];
    const float* Uib = (const float*)d_in[10];
    const float* Wo  = (const float*)d_in[11];
    const float* Wob = (const float*)d_in[12];
    const float* Uo  = (const float*)d_in[13];
    const float* Uob = (const float*)d_in[14];
    const float* Wc  = (const float*)d_in[15];
    const float* Wcb = (const float*)d_in[16];
    const float* Uc  = (const float*)d_in[17];
    const float* Ucb = (const float*)d_in[18];

    unsigned int* flags = (unsigned int*)d_ws;
    const int nflags = NGROUP * T_STEPS;

    lstm_init_flags<<<(nflags + 255) / 256, 256, 0, stream>>>(flags, nflags);
    lstm_persist<<<NGROUP * NSLICE, THREADS, 0, stream>>>(
        x, h0, c0,
        Wf, Wfb, Uf, Ufb, Wi, Wib, Ui, Uib,
        Wo, Wob, Uo, Uob, Wc, Wcb, Uc, Ucb,
        (float*)d_out, flags);
}

// Round 3
// 1565.191 us; speedup vs baseline: 1.8905x; 1.8905x over previous
//
#include <hip/hip_runtime.h>

// LSTM: SEQ=512, B=64, IN=256, H=512, fp32 in/out; bf16 MFMA compute.
// 4 batch-groups x 16 H-slice blocks (32 hid x 4 gates), persistent, 512 steps.
// Cross-block h exchange: write-through (sc0 sc1) atomic stores into d_out
// h_seq + per-(group,step) counter flag in d_ws. NO threadfence (no buffer_wbl2
// / buffer_inv): release = waitcnt vmcnt(0) + barrier + 1 atomic add per block;
// consumers poll flag with coherent load, then PLAIN cached loads of h (each
// address written exactly once, write-through, never pre-cached on consumer).
// LDS fragment-major (+16B/16frags pad): MFMA ds_read_b128 is stride-1.

#define T_STEPS 512
#define BATCH   64
#define IN_D    256
#define HID     512
#define NGROUP  4
#define NSLICE  16
#define BLK_B   16
#define BLK_H   32
#define THREADS 512

using short8  = __attribute__((ext_vector_type(8))) short;
using float4v = __attribute__((ext_vector_type(4))) float;

#define FRAG_ADDR(f) (((f) << 4) + (((f) >> 4) << 4))   // 16B frag + 16B pad per 16 frags

__device__ __forceinline__ unsigned short f2bf(float f) {
    union { float f; unsigned int i; } v; v.f = f;
    unsigned int r = v.i + 0x7fff + ((v.i >> 16) & 1);
    return (unsigned short)(r >> 16);
}
__device__ __forceinline__ short8 pack8(float4 a, float4 b) {
    short8 s;
    s[0]=(short)f2bf(a.x); s[1]=(short)f2bf(a.y); s[2]=(short)f2bf(a.z); s[3]=(short)f2bf(a.w);
    s[4]=(short)f2bf(b.x); s[5]=(short)f2bf(b.y); s[6]=(short)f2bf(b.z); s[7]=(short)f2bf(b.w);
    return s;
}
__device__ __forceinline__ float sigm(float v) { return 1.0f / (1.0f + __expf(-v)); }
__device__ __forceinline__ float tanh_(float v) { return 2.0f / (1.0f + __expf(-2.0f * v)) - 1.0f; }

__global__ __launch_bounds__(256, 1) void lstm_init_flags(unsigned int* flags, int n) {
    int i = blockIdx.x * blockDim.x + threadIdx.x;
    if (i < n) flags[i] = 0u;
}

__global__ __launch_bounds__(THREADS, 2) void lstm_persist(
    const float* __restrict__ x,
    const float* __restrict__ h0,
    const float* __restrict__ c0,
    const float* __restrict__ Wf, const float* __restrict__ Wfb,
    const float* __restrict__ Uf, const float* __restrict__ Ufb,
    const float* __restrict__ Wi, const float* __restrict__ Wib,
    const float* __restrict__ Ui, const float* __restrict__ Uib,
    const float* __restrict__ Wo, const float* __restrict__ Wob,
    const float* __restrict__ Uo, const float* __restrict__ Uob,
    const float* __restrict__ Wc, const float* __restrict__ Wcb,
    const float* __restrict__ Uc, const float* __restrict__ Ucb,
    float* out,                 // h_seq (T,B,H) | h (B,H) | c (B,H), fp32
    unsigned int* flags)        // [NGROUP][T] producer counters (target 16)
{
    // fragment-major LDS: frag f=(ks*64 + lq*16 + lm), 16B each, padded
    __shared__ __attribute__((aligned(16))) unsigned char hfrag[17392]; // 1024 frags
    __shared__ __attribute__((aligned(16))) unsigned char xfrag[8688];  // 512 frags
    __shared__ float g_lds[8 * 256];                                    // gate outputs

    const int tid  = threadIdx.x;
    const int lane = tid & 63;
    const int wave = tid >> 6;            // 0..7
    const int gate = wave >> 1;           // 0:f 1:i 2:o 3:c
    const int hlf  = wave & 1;            // 16-hid half of the 32
    const int grp  = blockIdx.x & 3;      // batch group
    const int slc  = blockIdx.x >> 2;     // hid slice
    const int bb   = grp * BLK_B;
    const int hbase= slc * BLK_H;
    const int lm   = lane & 15;
    const int lq   = lane >> 4;
    const int row  = tid >> 5;            // 0..15 (batch within group)
    const int seg  = tid & 31;            // 0..31

    const float* Ug  = (gate == 0) ? Uf : (gate == 1) ? Ui : (gate == 2) ? Uo : Uc;
    const float* Wg  = (gate == 0) ? Wf : (gate == 1) ? Wi : (gate == 2) ? Wo : Wc;
    const float* Wbg = (gate == 0) ? Wfb : (gate == 1) ? Wib : (gate == 2) ? Wob : Wcb;
    const float* Ubg = (gate == 0) ? Ufb : (gate == 1) ? Uib : (gate == 2) ? Uob : Ucb;
    const int ng = hbase + hlf * 16 + lm;   // lane's gate-output row (B-op n)

    // ---- register-resident bf16 weight fragments ----
    short8 ufrag[16];
#pragma unroll
    for (int ks = 0; ks < 16; ++ks) {
        const float* p = Ug + (size_t)ng * HID + ks * 32 + lq * 8;
        ufrag[ks] = pack8(*(const float4*)(p), *(const float4*)(p + 4));
    }
    short8 wfrag[8];
#pragma unroll
    for (int ks = 0; ks < 8; ++ks) {
        const float* p = Wg + (size_t)ng * IN_D + ks * 32 + lq * 8;
        wfrag[ks] = pack8(*(const float4*)(p), *(const float4*)(p + 4));
    }
    const float bias = Wbg[ng] + Ubg[ng];

    // ---- cell state in registers: thread (row,seg) owns c[row][hbase+seg] ----
    float c_reg = c0[(size_t)(bb + row) * HID + hbase + seg];

    // ---- stage h0 (2 frags/thread) and x0 (1 frag/thread) ----
    {
        const float* ph = h0 + (size_t)(bb + row) * HID + seg * 16;
        int f0 = (seg >> 1) * 64 + (seg & 1) * 32 + row;   // ks=seg/2, lq=(seg&1)*2
        *(short8*)(hfrag + FRAG_ADDR(f0))      = pack8(*(const float4*)(ph),     *(const float4*)(ph + 4));
        *(short8*)(hfrag + FRAG_ADDR(f0 + 16)) = pack8(*(const float4*)(ph + 8), *(const float4*)(ph + 12));

        const float* px = x + (size_t)(bb + row) * IN_D + seg * 8;
        int fx = (seg >> 2) * 64 + (seg & 3) * 16 + row;   // ks=seg/4, lq=seg%4
        *(short8*)(xfrag + FRAG_ADDR(fx)) = pack8(*(const float4*)(px), *(const float4*)(px + 4));
    }
    // prefetch x_1
    float4 xn0, xn1;
    {
        const float* px = x + ((size_t)1 * BATCH + bb + row) * IN_D + seg * 8;
        xn0 = *(const float4*)(px); xn1 = *(const float4*)(px + 4);
    }
    __syncthreads();

    // accx = bias + x_0 @ W^T
    float4v accx0 = {bias, bias, bias, bias};
    float4v accx1 = {0.f, 0.f, 0.f, 0.f};
#pragma unroll
    for (int ks = 0; ks < 8; ++ks) {
        short8 a = *(const short8*)(xfrag + FRAG_ADDR(ks * 64 + lane));
        if (ks & 1) accx1 = __builtin_amdgcn_mfma_f32_16x16x32_bf16(a, wfrag[ks], accx1, 0, 0, 0);
        else        accx0 = __builtin_amdgcn_mfma_f32_16x16x32_bf16(a, wfrag[ks], accx0, 0, 0, 0);
    }

    unsigned int* const cnt = flags + (size_t)grp * T_STEPS;
    float* const out_h = out + (size_t)T_STEPS * BATCH * HID;
    float* const out_c = out_h + (size_t)BATCH * HID;

    for (int t = 0; t < T_STEPS; ++t) {
        // ---- h-part MFMAs on top of accx ----
        float4v acc0 = accx0, acc1 = accx1;
#pragma unroll
        for (int ks = 0; ks < 16; ++ks) {
            short8 a = *(const short8*)(hfrag + FRAG_ADDR(ks * 64 + lane));
            if (ks & 1) acc1 = __builtin_amdgcn_mfma_f32_16x16x32_bf16(a, ufrag[ks], acc1, 0, 0, 0);
            else        acc0 = __builtin_amdgcn_mfma_f32_16x16x32_bf16(a, ufrag[ks], acc0, 0, 0, 0);
        }
        float4v acc = acc0 + acc1;
#pragma unroll
        for (int r = 0; r < 4; ++r)
            g_lds[wave * 256 + (lq * 4 + r) * 16 + lm] = acc[r];
        __syncthreads();   // A: gates visible; all hfrag/xfrag MFMA reads done

        // ---- pointwise (fp32, c in register) ----
        float hv;
        {
            int hf2 = seg >> 4, nn = seg & 15;
            float fpre = g_lds[(0 * 2 + hf2) * 256 + row * 16 + nn];
            float ipre = g_lds[(1 * 2 + hf2) * 256 + row * 16 + nn];
            float opre = g_lds[(2 * 2 + hf2) * 256 + row * 16 + nn];
            float gpre = g_lds[(3 * 2 + hf2) * 256 + row * 16 + nn];
            float fv = sigm(fpre), iv = sigm(ipre), ov = sigm(opre);
            float gv = tanh_(gpre);
            c_reg = fv * c_reg + iv * gv;
            hv = ov * tanh_(c_reg);
        }
        // write-through h store (sc0 sc1): visible at MALL once vmcnt drains
        __hip_atomic_store(out + ((size_t)t * BATCH + bb + row) * HID + hbase + seg,
                           hv, __ATOMIC_RELAXED, __HIP_MEMORY_SCOPE_AGENT);
        if (t == T_STEPS - 1) {
            out_h[(size_t)(bb + row) * HID + hbase + seg] = hv;
            out_c[(size_t)(bb + row) * HID + hbase + seg] = c_reg;
        }

        // ---- stage x_{t+1} frag from regs; prefetch x_{t+2} ----
        if (t + 1 < T_STEPS) {
            int fx = (seg >> 2) * 64 + (seg & 3) * 16 + row;
            *(short8*)(xfrag + FRAG_ADDR(fx)) = pack8(xn0, xn1);
            int tn = (t + 2 < T_STEPS) ? (t + 2) : (T_STEPS - 1);
            const float* px = x + ((size_t)tn * BATCH + bb + row) * IN_D + seg * 8;
            xn0 = *(const float4*)(px); xn1 = *(const float4*)(px + 4);
        }

        asm volatile("s_waitcnt vmcnt(0)" ::: "memory");  // h stores acked at MALL
        __syncthreads();   // A2: all waves' stores acked; xfrag(t+1) staged

        if (t + 1 < T_STEPS) {
            if (tid == 0)
                __hip_atomic_fetch_add(&cnt[t], 1u, __ATOMIC_RELAXED, __HIP_MEMORY_SCOPE_AGENT);

            // accx for t+1 — overlaps flag propagation latency
            accx0 = (float4v){bias, bias, bias, bias};
            accx1 = (float4v){0.f, 0.f, 0.f, 0.f};
#pragma unroll
            for (int ks = 0; ks < 8; ++ks) {
                short8 a = *(const short8*)(xfrag + FRAG_ADDR(ks * 64 + lane));
                if (ks & 1) accx1 = __builtin_amdgcn_mfma_f32_16x16x32_bf16(a, wfrag[ks], accx1, 0, 0, 0);
                else        accx0 = __builtin_amdgcn_mfma_f32_16x16x32_bf16(a, wfrag[ks], accx0, 0, 0, 0);
            }

            if (tid == 0) {
                while (__hip_atomic_load(&cnt[t], __ATOMIC_RELAXED, __HIP_MEMORY_SCOPE_AGENT)
                       < (unsigned)NSLICE) { /* spin */ }
            }
            __syncthreads();   // B: h_t published by all 16 producers

            // ---- stage h_t: plain cached loads (write-once addresses), pack ----
            {
                const float* src = out + ((size_t)t * BATCH + bb + row) * HID + seg * 16;
                float4 a0 = *(const float4*)(src);
                float4 a1 = *(const float4*)(src + 4);
                float4 a2 = *(const float4*)(src + 8);
                float4 a3 = *(const float4*)(src + 12);
                int f0 = (seg >> 1) * 64 + (seg & 1) * 32 + row;
                *(short8*)(hfrag + FRAG_ADDR(f0))      = pack8(a0, a1);
                *(short8*)(hfrag + FRAG_ADDR(f0 + 16)) = pack8(a2, a3);
            }
            __syncthreads();   // C: hfrag ready for next iteration's MFMAs
        }
    }
}

extern "C" void kernel_launch(void* const* d_in, const int* in_sizes, int n_in,
                              void* d_out, int out_size, void* d_ws, size_t ws_size,
                              hipStream_t stream) {
    (void)in_sizes; (void)n_in; (void)out_size; (void)ws_size;
    const float* x   = (const float*)d_in[0];
    const float* h0  = (const float*)d_in[1];
    const float* c0  = (const float*)d_in[2];
    const float* Wf  = (const float*)d_in[3];
    const float* Wfb = (const float*)d_in[4];
    const float* Uf  = (const float*)d_in[5];
    const float* Ufb = (const float*)d_in[6];
    const float* Wi  = (const float*)d_in[7];
    const float* Wib = (const float*)d_in[8];
    const float* Ui  = (const float*)d_in[9];
    const float* Uib = (const float*)d_in[10];
    const float* Wo  = (const float*)d_in[11];
    const float* Wob = (const float*)d_in[12];
    const float* Uo  = (const float*)d_in[13];
    const float* Uob = (const float*)d_in[14];
    const float* Wc  = (const float*)d_in[15];
    const float* Wcb = (const float*)d_in[16];
    const float* Uc  = (const float*)d_in[17];
    const float* Ucb = (const float*)d_in[18];

    unsigned int* flags = (unsigned int*)d_ws;
    const int nflags = NGROUP * T_STEPS;

    lstm_init_flags<<<(nflags + 255) / 256, 256, 0, stream>>>(flags, nflags);
    lstm_persist<<<NGROUP * NSLICE, THREADS, 0, stream>>>(
        x, h0, c0,
        Wf, Wfb, Uf, Ufb, Wi, Wib, Ui, Uib,
        Wo, Wob, Uo, Uob, Wc, Wcb, Uc, Ucb,
        (float*)d_out, flags);
}